// Round 1
// baseline (382.712 us; speedup 1.0000x reference)
//
#include <hip/hip_runtime.h>
#include <hip/hip_bf16.h>

// FusionRetrModel: B=4, NL=2 (only l=1 used), P=100, TOK=60, T=6000, D=768.
// Pipeline:
//   prep: Qpad bf16 [4][6016][768]; Wpb/Wtb[b][d][k] = Wp2+A*Wp3 (bf16);
//         cp/ct[b][d] = A@Wp1^T + bias; Wf1 cast bf16.
//   gemm1: ps = Qpad @ Wpb^T + cp   (bf16 MFMA, K=768)
//   gemm2: ts = Qpad @ Wtb^T + ct
//   tmax:  per-table elementwise max over passages
//   gather: aggr[b][r][k] = tmax[b][ids[p]][tok][k]  (reuses Qpad region)
//   gemm3: Hpre = [ps|aggr] @ Wf1^T  (K=1536, split A source; reuses ts region)
//   score: out[b,p] = sum_tok mask * (sum_d relu(Hpre+bf1)*w2 + bf2)
// Workspace: ~126.4 MB required.

typedef unsigned short u16;
typedef unsigned int u32;
typedef __attribute__((ext_vector_type(8))) short bf16x8;
typedef __attribute__((ext_vector_type(4))) float f32x4;

#define NUM_TABLES 10
#define MPAD 6016
#define DD 768

__device__ __forceinline__ u16 f2bf(float f) {
  u32 u = __builtin_bit_cast(u32, f);
  u32 r = u + 0x7FFFu + ((u >> 16) & 1u);
  return (u16)(r >> 16);
}
__device__ __forceinline__ float bf2f(u16 h) {
  u32 u = ((u32)h) << 16;
  return __builtin_bit_cast(float, u);
}

__device__ __forceinline__ void gload_lds16(const u16* g, u16* l) {
  __builtin_amdgcn_global_load_lds(
      (const __attribute__((address_space(1))) void*)g,
      (__attribute__((address_space(3))) void*)l, 16, 0, 0);
}

// ---------------- prep kernels ----------------

// cast Q (l=1 slice) to bf16, pad rows [6000,6016) with zeros. 8 elems/thread.
__global__ void prep_q(const float* __restrict__ qps, uint4* __restrict__ qpad) {
  size_t c = (size_t)blockIdx.x * 256 + threadIdx.x;
  const int per_b = MPAD * (DD / 8);
  if (c >= (size_t)4 * per_b) return;
  int b = (int)(c / per_b);
  int rr = (int)(c % per_b);
  int r = rr / (DD / 8);
  int kc = rr % (DD / 8);
  uint4 o;
  if (r < 6000) {
    const float* src = qps + (((size_t)(b * 2 + 1)) * 6000 + r) * DD + kc * 8;
    float4 f0 = *(const float4*)src;
    float4 f1 = *(const float4*)(src + 4);
    o.x = (u32)f2bf(f0.x) | ((u32)f2bf(f0.y) << 16);
    o.y = (u32)f2bf(f0.z) | ((u32)f2bf(f0.w) << 16);
    o.z = (u32)f2bf(f1.x) | ((u32)f2bf(f1.y) << 16);
    o.w = (u32)f2bf(f1.z) | ((u32)f2bf(f1.w) << 16);
  } else {
    o = make_uint4(0, 0, 0, 0);
  }
  qpad[c] = o;
}

// Wpb[b][d][k] = Wp[d][768+k] + A[b][k]*Wp[d][1536+k]; same for Wt. 4 elems/thread.
__global__ void prep_wcomb(const float* __restrict__ Ans, const float* __restrict__ Wp,
                           const float* __restrict__ Wt,
                           u16* __restrict__ Wpb, u16* __restrict__ Wtb) {
  size_t c = (size_t)blockIdx.x * 256 + threadIdx.x;
  const int per_b = DD * (DD / 4);
  if (c >= (size_t)4 * per_b) return;
  int b = (int)(c / per_b);
  int rr = (int)(c % per_b);
  int d = rr / (DD / 4);
  int k4 = (rr % (DD / 4)) * 4;
  float4 av = *(const float4*)(Ans + ((size_t)b * 2 + 1) * DD + k4);
  float4 p2 = *(const float4*)(Wp + (size_t)d * 2304 + 768 + k4);
  float4 p3 = *(const float4*)(Wp + (size_t)d * 2304 + 1536 + k4);
  float4 t2 = *(const float4*)(Wt + (size_t)d * 2304 + 768 + k4);
  float4 t3 = *(const float4*)(Wt + (size_t)d * 2304 + 1536 + k4);
  uint2 op, ot;
  op.x = (u32)f2bf(p2.x + av.x * p3.x) | ((u32)f2bf(p2.y + av.y * p3.y) << 16);
  op.y = (u32)f2bf(p2.z + av.z * p3.z) | ((u32)f2bf(p2.w + av.w * p3.w) << 16);
  ot.x = (u32)f2bf(t2.x + av.x * t3.x) | ((u32)f2bf(t2.y + av.y * t3.y) << 16);
  ot.y = (u32)f2bf(t2.z + av.z * t3.z) | ((u32)f2bf(t2.w + av.w * t3.w) << 16);
  size_t idx = ((size_t)b * DD + d) * DD + k4;
  *(uint2*)(Wpb + idx) = op;
  *(uint2*)(Wtb + idx) = ot;
}

// cp[b][d] = sum_k A[b][k]*Wp[d][k] + bp[d]; ct likewise.
__global__ void prep_consts(const float* __restrict__ Ans, const float* __restrict__ Wp,
                            const float* __restrict__ bp, const float* __restrict__ Wt,
                            const float* __restrict__ bt,
                            float* __restrict__ cp, float* __restrict__ ct) {
  int idx = blockIdx.x * 256 + threadIdx.x;
  if (idx >= 4 * DD) return;
  int b = idx / DD, d = idx % DD;
  const float* a = Ans + ((size_t)b * 2 + 1) * DD;
  const float* wp = Wp + (size_t)d * 2304;
  const float* wt = Wt + (size_t)d * 2304;
  float sp = 0.f, st = 0.f;
  for (int k = 0; k < DD; k += 4) {
    float4 av = *(const float4*)(a + k);
    float4 pv = *(const float4*)(wp + k);
    float4 tv = *(const float4*)(wt + k);
    sp += av.x * pv.x + av.y * pv.y + av.z * pv.z + av.w * pv.w;
    st += av.x * tv.x + av.y * tv.y + av.z * tv.z + av.w * tv.w;
  }
  cp[idx] = sp + bp[d];
  ct[idx] = st + bt[d];
}

// cast Wf1 [768][1536] to bf16 (same layout). 8 elems/thread.
__global__ void prep_wf1(const float* __restrict__ Wf1, uint4* __restrict__ Wf1b) {
  size_t c = (size_t)blockIdx.x * 256 + threadIdx.x;
  if (c >= (size_t)DD * 1536 / 8) return;
  const float* src = Wf1 + c * 8;
  float4 f0 = *(const float4*)src;
  float4 f1 = *(const float4*)(src + 4);
  uint4 o;
  o.x = (u32)f2bf(f0.x) | ((u32)f2bf(f0.y) << 16);
  o.y = (u32)f2bf(f0.z) | ((u32)f2bf(f0.w) << 16);
  o.z = (u32)f2bf(f1.x) | ((u32)f2bf(f1.y) << 16);
  o.w = (u32)f2bf(f1.z) | ((u32)f2bf(f1.w) << 16);
  Wf1b[c] = o;
}

// ---------------- MFMA GEMM (C[m][n] = sum_k A[m][k]*B[n][k], bf16 in/out, f32 acc) ----------------
// 128x128 tile, BK=64, 256 threads (4 waves, 2x2), each wave 64x64 (4x4 frags of 16x16x32).
// A source splits at kSplit (feat=[ps|aggr] for gemm3); A row stride fixed at 768 elems.
__global__ __launch_bounds__(256, 2)
void gemm_bt(const u16* __restrict__ A0, const u16* __restrict__ A1,
             const u16* __restrict__ Bm, const float* __restrict__ cvec,
             u16* __restrict__ C, int K, int kSplit, int strideB) {
  const int b = blockIdx.z;
  const int m0 = blockIdx.x * 128;
  const int n0 = blockIdx.y * 128;
  const int tid = threadIdx.x;
  const int lane = tid & 63;
  const int wid = tid >> 6;
  const int wm = wid >> 1, wn = wid & 1;

  __shared__ u16 As[128 * 64];
  __shared__ u16 Bs[128 * 64];

  const u16* Abase0 = A0 + (size_t)b * MPAD * DD;
  const u16* Abase1 = A1 + (size_t)b * MPAD * DD;
  const u16* Bbase = Bm + (size_t)b * strideB;

  f32x4 acc[4][4] = {};

  const int lrow = lane >> 3;        // 0..7 (row within 8-row chunk)
  const int lcol = (lane & 7) * 8;   // element col within 64

  for (int kt = 0; kt < K / 64; ++kt) {
    const int k0 = kt * 64;
    const u16* Asrc;
    int kk;
    if (k0 < kSplit) { Asrc = Abase0; kk = k0; }
    else             { Asrc = Abase1; kk = k0 - kSplit; }
#pragma unroll
    for (int j = 0; j < 4; ++j) {
      const u16* g = Asrc + (size_t)(m0 + wid * 32 + j * 8 + lrow) * DD + kk + lcol;
      gload_lds16(g, &As[(wid * 32 + j * 8) * 64]);
    }
#pragma unroll
    for (int j = 0; j < 4; ++j) {
      const u16* g = Bbase + (size_t)(n0 + wid * 32 + j * 8 + lrow) * K + k0 + lcol;
      gload_lds16(g, &Bs[(wid * 32 + j * 8) * 64]);
    }
    __syncthreads();

    bf16x8 af[2][4], bfr[2][4];
#pragma unroll
    for (int kf = 0; kf < 2; ++kf)
#pragma unroll
      for (int mf = 0; mf < 4; ++mf)
        af[kf][mf] = *(const bf16x8*)&As[(wm * 64 + mf * 16 + (lane & 15)) * 64 + kf * 32 + (lane >> 4) * 8];
#pragma unroll
    for (int kf = 0; kf < 2; ++kf)
#pragma unroll
      for (int nf = 0; nf < 4; ++nf)
        bfr[kf][nf] = *(const bf16x8*)&Bs[(wn * 64 + nf * 16 + (lane & 15)) * 64 + kf * 32 + (lane >> 4) * 8];

#pragma unroll
    for (int mf = 0; mf < 4; ++mf)
#pragma unroll
      for (int nf = 0; nf < 4; ++nf) {
        acc[mf][nf] = __builtin_amdgcn_mfma_f32_16x16x32_bf16(af[0][mf], bfr[0][nf], acc[mf][nf], 0, 0, 0);
        acc[mf][nf] = __builtin_amdgcn_mfma_f32_16x16x32_bf16(af[1][mf], bfr[1][nf], acc[mf][nf], 0, 0, 0);
      }
    __syncthreads();
  }

  const float* cv = cvec ? cvec + b * DD : nullptr;
  u16* Cb = C + (size_t)b * MPAD * DD;
#pragma unroll
  for (int mf = 0; mf < 4; ++mf)
#pragma unroll
    for (int nf = 0; nf < 4; ++nf)
#pragma unroll
      for (int r = 0; r < 4; ++r) {
        int row = m0 + wm * 64 + mf * 16 + (lane >> 4) * 4 + r;
        int col = n0 + wn * 64 + nf * 16 + (lane & 15);
        float v = acc[mf][nf][r];
        if (cv) v += cv[col];
        Cb[(size_t)row * DD + col] = f2bf(v);
      }
}

// ---------------- table max ----------------
// tmax[b][t][tok][d] = max over p with ids[b][p]==t of ts[b][p*60+tok][d]
__global__ void table_max_kernel(const u16* __restrict__ ts, const int* __restrict__ ids,
                                 u16* __restrict__ tmax) {
  int bi = blockIdx.x;  // 4*60*3 = 720
  int b = bi / 180;
  int rem = bi % 180;
  int tok = rem / 3;
  int dc = rem % 3;
  int d = dc * 256 + threadIdx.x;
  __shared__ int sids[100];
  if (threadIdx.x < 100) sids[threadIdx.x] = ids[b * 100 + threadIdx.x];
  __syncthreads();
  float m[NUM_TABLES];
#pragma unroll
  for (int t = 0; t < NUM_TABLES; ++t) m[t] = -INFINITY;
  const u16* base = ts + ((size_t)b * MPAD + tok) * DD + d;
  for (int p = 0; p < 100; ++p) {
    float v = bf2f(base[(size_t)p * 60 * DD]);
    int id = sids[p];
#pragma unroll
    for (int t = 0; t < NUM_TABLES; ++t)
      if (id == t) m[t] = fmaxf(m[t], v);
  }
#pragma unroll
  for (int t = 0; t < NUM_TABLES; ++t)
    tmax[(((size_t)b * NUM_TABLES + t) * 60 + tok) * DD + d] = f2bf(m[t]);
}

// aggr[b][r][k] = tmax[b][ids[b][r/60]][r%60][k]; pad rows -> 0. 8 elems/thread.
__global__ void gather_aggr(const u16* __restrict__ tmax, const int* __restrict__ ids,
                            uint4* __restrict__ aggr) {
  size_t c = (size_t)blockIdx.x * 256 + threadIdx.x;
  const int per_b = MPAD * (DD / 8);
  if (c >= (size_t)4 * per_b) return;
  int b = (int)(c / per_b);
  int rr = (int)(c % per_b);
  int r = rr / (DD / 8);
  int kc = rr % (DD / 8);
  uint4 v;
  if (r < 6000) {
    int p = r / 60, tok = r % 60;
    int id = ids[b * 100 + p];
    v = *(const uint4*)(tmax + (((size_t)b * NUM_TABLES + id) * 60 + tok) * DD + kc * 8);
  } else {
    v = make_uint4(0, 0, 0, 0);
  }
  aggr[c] = v;
}

// ---------------- final scoring ----------------
// out[b,p] = sum_{tok,d} mask[tok]*relu(H+bf1[d])*w2[d] + bf2*sum_tok mask[tok]
__global__ __launch_bounds__(256) void score_kernel(const u16* __restrict__ H,
    const float* __restrict__ bf1, const float* __restrict__ w2,
    const float* __restrict__ bf2, const float* __restrict__ mask,
    float* __restrict__ out) {
  int bp_ = blockIdx.x;  // 400
  int b = bp_ / 100, p = bp_ % 100;
  const u16* Hb = H + ((size_t)b * MPAD + p * 60) * DD;
  const float* mrow = mask + ((size_t)b * 100 + p) * 60;
  float acc = 0.f;
  for (int idx = threadIdx.x; idx < 60 * (DD / 8); idx += 256) {
    int tok = idx / (DD / 8);
    int d0 = (idx % (DD / 8)) * 8;
    uint4 hv = *(const uint4*)(Hb + (size_t)tok * DD + d0);
    float mk = mrow[tok];
    float4 b0 = *(const float4*)(bf1 + d0);
    float4 b1 = *(const float4*)(bf1 + d0 + 4);
    float4 w0 = *(const float4*)(w2 + d0);
    float4 w1 = *(const float4*)(w2 + d0 + 4);
    float s = 0.f;
    float h;
    h = bf2f((u16)(hv.x & 0xFFFF)) + b0.x; s += fmaxf(h, 0.f) * w0.x;
    h = bf2f((u16)(hv.x >> 16))    + b0.y; s += fmaxf(h, 0.f) * w0.y;
    h = bf2f((u16)(hv.y & 0xFFFF)) + b0.z; s += fmaxf(h, 0.f) * w0.z;
    h = bf2f((u16)(hv.y >> 16))    + b0.w; s += fmaxf(h, 0.f) * w0.w;
    h = bf2f((u16)(hv.z & 0xFFFF)) + b1.x; s += fmaxf(h, 0.f) * w1.x;
    h = bf2f((u16)(hv.z >> 16))    + b1.y; s += fmaxf(h, 0.f) * w1.y;
    h = bf2f((u16)(hv.w & 0xFFFF)) + b1.z; s += fmaxf(h, 0.f) * w1.z;
    h = bf2f((u16)(hv.w >> 16))    + b1.w; s += fmaxf(h, 0.f) * w1.w;
    acc += mk * s;
  }
  float msum = (threadIdx.x < 60) ? mrow[threadIdx.x] : 0.f;
#pragma unroll
  for (int off = 32; off > 0; off >>= 1) {
    acc += __shfl_down(acc, off);
    msum += __shfl_down(msum, off);
  }
  __shared__ float red[8];
  int wid = threadIdx.x >> 6;
  if ((threadIdx.x & 63) == 0) { red[wid] = acc; red[4 + wid] = msum; }
  __syncthreads();
  if (threadIdx.x == 0) {
    float a = red[0] + red[1] + red[2] + red[3];
    float m = red[4] + red[5] + red[6] + red[7];
    out[b * 100 + p] = a + bf2[0] * m;
  }
}

// ---------------- launch ----------------
extern "C" void kernel_launch(void* const* d_in, const int* in_sizes, int n_in,
                              void* d_out, int out_size, void* d_ws, size_t ws_size,
                              hipStream_t stream) {
  const float* answer = (const float*)d_in[0];
  const float* qps    = (const float*)d_in[1];
  const float* mask   = (const float*)d_in[2];
  const int*   tids   = (const int*)d_in[3];
  const float* Wp     = (const float*)d_in[4];
  const float* bp     = (const float*)d_in[5];
  const float* Wt     = (const float*)d_in[6];
  const float* bt     = (const float*)d_in[7];
  const float* Wf1    = (const float*)d_in[8];
  const float* bf1    = (const float*)d_in[9];
  const float* Wf2    = (const float*)d_in[10];
  const float* bf2    = (const float*)d_in[11];
  float* out = (float*)d_out;

  char* ws = (char*)d_ws;
  // region layout (bytes); total 126,394,368
  u16* Qpad = (u16*)(ws + 0);            // 36,962,304  (reused as aggr)
  u16* ps   = (u16*)(ws + 36962304);     // 36,962,304
  u16* ts   = (u16*)(ws + 73924608);     // 36,962,304  (reused as Hpre)
  u16* Wpb  = (u16*)(ws + 110886912);    // 4,718,592
  u16* Wtb  = (u16*)(ws + 115605504);    // 4,718,592
  u16* Wf1b = (u16*)(ws + 120324096);    // 2,359,296
  float* cp = (float*)(ws + 122683392);  // 12,288
  float* ct = (float*)(ws + 122695680);  // 12,288
  u16* tmax = (u16*)(ws + 122707968);    // 3,686,400

  prep_q<<<9024, 256, 0, stream>>>(qps, (uint4*)Qpad);
  prep_wcomb<<<2304, 256, 0, stream>>>(answer, Wp, Wt, Wpb, Wtb);
  prep_consts<<<12, 256, 0, stream>>>(answer, Wp, bp, Wt, bt, cp, ct);
  prep_wf1<<<576, 256, 0, stream>>>(Wf1, (uint4*)Wf1b);

  dim3 g2(47, 6, 4);
  // ps = Qpad @ Wpb^T + cp
  gemm_bt<<<g2, 256, 0, stream>>>(Qpad, Qpad, Wpb, cp, ps, 768, 768, 768 * 768);
  // ts = Qpad @ Wtb^T + ct
  gemm_bt<<<g2, 256, 0, stream>>>(Qpad, Qpad, Wtb, ct, ts, 768, 768, 768 * 768);

  table_max_kernel<<<720, 256, 0, stream>>>(ts, tids, tmax);
  gather_aggr<<<9024, 256, 0, stream>>>(tmax, tids, (uint4*)Qpad);  // aggr into Qpad

  // Hpre = [ps | aggr] @ Wf1^T   (into ts region)
  gemm_bt<<<g2, 256, 0, stream>>>(ps, Qpad, Wf1b, nullptr, ts, 1536, 768, 0);

  score_kernel<<<400, 256, 0, stream>>>(ts, bf1, Wf2, bf2, mask, out);
}